// Round 14
// baseline (15.250 us; speedup 1.0000x reference)
//
#include <hip/hip_runtime.h>

// ---------------------------------------------------------------------------
// Quantum conv2d, MFMA edition v5.
// v4 + (a) pre-padded LDS tile [4 rows][4 ch][66 cols] -> zero per-channel
// column guards, (b) permlane32_swap for the t1 cross-lane stage, (c) hoisted
// zero accumulator for the MFMA C operand.
// Row/K convention (validated R8): row 2m = Re(amp), 2m+1 = Im(amp); K slot
// 2n = Re, 2n+1 = Im -> MFMA acc pairs are (Re,Im) of one amp, state = f2[8],
// cascade fully on v_pk_fma_f32, B-pack = cvt_pkrtz(re,im). 6 rsq, 0 sqrt.
// ---------------------------------------------------------------------------

typedef float     f2      __attribute__((ext_vector_type(2)));
typedef __fp16    fp16x2  __attribute__((ext_vector_type(2)));
typedef _Float16  half8_t __attribute__((ext_vector_type(8)));
typedef float     f32x16  __attribute__((ext_vector_type(16)));
typedef int       i2v     __attribute__((ext_vector_type(2)));

union H8   { fp16x2 h2[4]; half8_t h8; };
union AccW { f32x16 a; f2 w[8]; };

// partner value across the lane<32 / lane>=32 split
__device__ __forceinline__ float partner32(float v, int hi) {
#if __has_builtin(__builtin_amdgcn_permlane32_swap)
    const i2v r = __builtin_amdgcn_permlane32_swap(
        __float_as_int(v), __float_as_int(v), false, false);
    return __int_as_float(hi ? r.x : r.y);
#else
    return __shfl_xor(v, 32);
#endif
}

// ---------- f2 complex helpers (setup phase: evolve U columns) ----------
__device__ __forceinline__ f2 pkfma(f2 a, f2 b, f2 c) {
    return __builtin_elementwise_fma(a, b, c);
}
__device__ __forceinline__ f2 swap2(f2 v) {
    return __builtin_shufflevector(v, v, 1, 0);
}

struct GateM { f2 m00rr, m00ni, m01rr, m01ni, m10rr, m10ni, m11rr, m11ni; };

__device__ __forceinline__ GateM load_gate(const float* gp) {
    const float4* p = (const float4*)gp;
    const float4 e0 = p[0], e1 = p[1], e2 = p[2], e3 = p[3];
    GateM G;
    G.m00rr = f2{e0.x, e0.y}; G.m00ni = f2{e0.z, e0.w};
    G.m01rr = f2{e1.x, e1.y}; G.m01ni = f2{e1.z, e1.w};
    G.m10rr = f2{e2.x, e2.y}; G.m10ni = f2{e2.z, e2.w};
    G.m11rr = f2{e3.x, e3.y}; G.m11ni = f2{e3.z, e3.w};
    return G;
}

template<int STRIDE>
__device__ __forceinline__ void apply_gate(f2* s, const GateM G) {
    #pragma unroll
    for (int m0 = 0; m0 < 16; ++m0) {
        if (m0 & STRIDE) continue;
        const int m1 = m0 | STRIDE;
        const f2 a = s[m0], b = s[m1];
        const f2 as = swap2(a), bs = swap2(b);
        f2 o0 = G.m00rr * a;
        o0 = pkfma(G.m00ni, as, o0);
        o0 = pkfma(G.m01rr, b,  o0);
        o0 = pkfma(G.m01ni, bs, o0);
        f2 o1 = G.m10rr * a;
        o1 = pkfma(G.m10ni, as, o1);
        o1 = pkfma(G.m11rr, b,  o1);
        o1 = pkfma(G.m11ni, bs, o1);
        s[m0] = o0; s[m1] = o1;
    }
}

template<int BC, int BT>
__device__ __forceinline__ void apply_cnot(f2* s) {
    #pragma unroll
    for (int m = 0; m < 16; ++m) {
        if ((m & BC) && !(m & BT)) {
            const int m2 = m | BT;
            const f2 t = s[m]; s[m] = s[m2]; s[m2] = t;
        }
    }
}

// Packed rotation on (re,im) pairs: a' = c*a - s*b ; b' = s*a + c*b
#define PKROT(a, b, cc, ss) { \
    const f2 _na = __builtin_elementwise_fma(cc, a, -((ss) * (b))); \
    const f2 _nb = __builtin_elementwise_fma(ss, a,  ((cc) * (b))); \
    (a) = _na; (b) = _nb; }

__global__ __launch_bounds__(256, 4) void qconv_kernel(
        const float* __restrict__ x,     // (32, 4, 64, 64)
        const float* __restrict__ wts,   // (4, 2, 4, 3)
        float* __restrict__ out) {       // (32, 16, 64, 64)
    __shared__ float   smat[32 * 16];      // 2 KB packed gate coeffs
    __shared__ float   tile[4 * 4 * 66];   // 4.1 KB padded rows 2ry-1..2ry+2
    __shared__ f2      ucol[4 * 16 * 16];  // 8 KB U columns (complex f32)
    __shared__ half8_t ufrag[4 * 2 * 64];  // 4 KB A-fragments [ch][mfma][lane]

    const int tid = threadIdx.x;
    const int blk = blockIdx.x;          // 1024 blocks
    const int b  = blk >> 5;             // image
    const int ry = blk & 31;             // rows 2ry, 2ry+1

    // --- stage padded input tile: [r][ch][c], c=0..65 <-> gx=c-1 ---
    const float* xb = x + (size_t)b * 16384;
    #pragma unroll
    for (int i = 0; i < 5; ++i) {
        const int e = tid + i * 256;
        if (e < 1056) {
            const int r = e / 264, rem = e - r * 264;
            const int ch = rem / 66, c = rem - ch * 66;
            const int gy = 2 * ry - 1 + r;
            const int gx = c - 1;
            const int gyc = min(max(gy, 0), 63);
            const int gxc = min(max(gx, 0), 63);
            float val = xb[ch * 4096 + gyc * 64 + gxc];
            const bool in = ((unsigned)gy < 64u) && ((unsigned)gx < 64u);
            tile[e] = in ? val : 0.01f;
        }
    }

    // --- build packed Rot matrices (one thread per gate) ---
    if (tid < 32) {
        const float phi   = wts[tid*3 + 0];
        const float theta = wts[tid*3 + 1];
        const float omega = wts[tid*3 + 2];
        float st, ct; __sincosf(0.5f * theta,         &st, &ct);
        float sA, cA; __sincosf(0.5f * (phi + omega), &sA, &cA);
        float sB, cB; __sincosf(0.5f * (phi - omega), &sB, &cB);
        float* g = &smat[tid * 16];
        g[0]  =  cA*ct; g[1]  =  cA*ct; g[2]  =  sA*ct; g[3]  = -sA*ct; // m00
        g[4]  = -cB*st; g[5]  = -cB*st; g[6]  =  sB*st; g[7]  = -sB*st; // m01
        g[8]  =  cB*st; g[9]  =  cB*st; g[10] =  sB*st; g[11] = -sB*st; // m10
        g[12] =  cA*ct; g[13] =  cA*ct; g[14] = -sA*ct; g[15] =  sA*ct; // m11
    }
    __syncthreads();

    // --- evolve U columns: thread t<64 owns (ch = t>>4, col = t&15) ---
    if (tid < 64) {
        const int ch = tid >> 4, col = tid & 15;
        f2 u[16];
        #pragma unroll
        for (int j = 0; j < 16; ++j)
            u[j] = (j == col) ? f2{1.f, 0.f} : f2{0.f, 0.f};
        const float* cb = smat + ch * 128;
        apply_gate<8>(u, load_gate(cb + 0*16));
        apply_gate<4>(u, load_gate(cb + 1*16));
        apply_gate<2>(u, load_gate(cb + 2*16));
        apply_gate<1>(u, load_gate(cb + 3*16));
        apply_cnot<8, 4>(u); apply_cnot<4, 2>(u);
        apply_cnot<2, 1>(u); apply_cnot<1, 8>(u);
        apply_gate<8>(u, load_gate(cb + 4*16));
        apply_gate<4>(u, load_gate(cb + 5*16));
        apply_gate<2>(u, load_gate(cb + 6*16));
        apply_gate<1>(u, load_gate(cb + 7*16));
        apply_cnot<8, 2>(u); apply_cnot<4, 1>(u);
        apply_cnot<2, 8>(u); apply_cnot<1, 4>(u);
        #pragma unroll
        for (int j = 0; j < 16; ++j)
            ucol[(ch * 16 + col) * 16 + j] = u[j];   // ucol[ch][in][out]
    }
    __syncthreads();

    // --- build A-fragments with interleaved (Re,Im) row/K convention ---
    {
        const int ch = tid >> 6, l = tid & 63;
        const int mrow = l & 31, kf = l >> 5;
        const int hr = (mrow >> 2) & 1;
        const int ii = (mrow & 3) | ((mrow >> 3) << 2);
        const int jj = ii >> 1, pr = ii & 1;
        const int amp_out = (jj < 4) ? 4*hr + jj : 4*hr + jj + 4;
        #pragma unroll
        for (int m = 0; m < 2; ++m) {
            half8_t f;
            #pragma unroll
            for (int i = 0; i < 8; ++i) {
                const int n = i >> 1, pk = i & 1;
                const int jin = 4*m + n;
                const int amp_in = (jin < 4) ? 4*kf + jin : 4*kf + jin + 4;
                const f2 e = ucol[(ch * 16 + amp_in) * 16 + amp_out];
                const float val = pr ? (pk ? e.x : e.y) : (pk ? -e.y : e.x);
                f[i] = (_Float16)val;
            }
            ufrag[(ch * 2 + m) * 64 + l] = f;
        }
    }
    __syncthreads();

    // --- main: wave w (0-3) -> row 2ry+(w>>1), cols 32*(w&1)+..; 2 lanes/px ---
    const int wv = tid >> 6, lane = tid & 63;
    const int hi = lane >> 5;                 // amp-half this lane owns
    const int row = 2 * ry + (wv >> 1);
    const int xc = ((wv & 1) << 5) + (lane & 31);
    const int tr0 = (wv >> 1);                // tile row base for dy=0

    // state: S.w[j] = (Re, Im) of amp alpha(hi, j)
    AccW S;
    #pragma unroll
    for (int j = 0; j < 8; ++j) S.w[j] = f2{0.f, 0.f};
    S.w[0].x = hi ? 0.f : 1.f;                // |0>

    const f32x16 kZero = {};                  // hoisted MFMA C operand
    constexpr float EPS = 1e-30f;

    #pragma unroll
    for (int ic = 0; ic < 4; ++ic) {
        // ---- A fragments early: ds_read_b128 latency hides under cascade ----
        const half8_t A0 = ufrag[(ic * 2 + 0) * 64 + lane];
        const half8_t A1 = ufrag[(ic * 2 + 1) * 64 + lane];

        // ---- raw 3x3 patch, guard-free (tile pre-padded) ----
        float xv[9];
        #pragma unroll
        for (int dy = 0; dy < 3; ++dy) {
            const float* rowp = tile + ((tr0 + dy) * 4 + ic) * 66 + xc;
            xv[dy*3 + 0] = rowp[0];
            xv[dy*3 + 1] = rowp[1];
            xv[dy*3 + 2] = rowp[2];
        }

        // ---- pairwise sums of squares ----
        const float s01 = fmaf(xv[0], xv[0], xv[1]*xv[1]);
        const float s23 = fmaf(xv[2], xv[2], xv[3]*xv[3]);
        const float s45 = fmaf(xv[4], xv[4], xv[5]*xv[5]);
        const float s67 = fmaf(xv[6], xv[6], xv[7]*xv[7]);
        const float s03 = s01 + s23, s47 = s45 + s67, s07 = s03 + s47;
        const float Sf  = fmaf(xv[8], xv[8], s07);

        // ---- per-half raw/sum selection ----
        const float a_  = hi ? xv[4] : xv[0], b_  = hi ? xv[5] : xv[1];
        const float c_  = hi ? xv[6] : xv[2], d_  = hi ? xv[7] : xv[3];
        const float sab = hi ? s45 : s01,     scd = hi ? s67 : s23;

        // ---- 6 rsq, zero sqrt ----
        const float rAB = __builtin_amdgcn_rsqf(sab + EPS);
        const float rCD = __builtin_amdgcn_rsqf(scd + EPS);
        const float r03 = __builtin_amdgcn_rsqf(s03 + EPS);
        const float r47 = __builtin_amdgcn_rsqf(s47 + EPS);
        const float r07 = __builtin_amdgcn_rsqf(s07 + EPS);
        const float rS  = __builtin_amdgcn_rsqf(Sf  + EPS);
        const float rS4 = hi ? r47 : r03;

        // ---- node coefficients via telescoped products ----
        const float c0  = s07 * r07 * rS,   s0  = xv[8] * rS;
        const float c1  = s03 * r03 * r07,  s1v = s47 * r47 * r07;
        const float c2e = sab * rAB * rS4,  s2e = scd * rCD * rS4;
        const float c3x = a_ * rAB,         s3x = b_ * rAB;
        const float c3y = c_ * rCD,         s3y = d_ * rCD;
        const float bs1 = hi ? s1v : -s1v;

        // broadcast to packed coeffs
        const f2 c0f = f2{c0, c0},   s0f = f2{s0, s0};
        const f2 c1f = f2{c1, c1},   b1f = f2{bs1, bs1};
        const f2 c2f = f2{c2e, c2e}, s2f = f2{s2e, s2e};
        const f2 c3xf = f2{c3x, c3x}, s3xf = f2{s3x, s3x};
        const f2 c3yf = f2{c3y, c3y}, s3yf = f2{s3y, s3y};

        // ---- cascade, fully packed ----
        PKROT(S.w[0], S.w[4], c0f, s0f);
        PKROT(S.w[1], S.w[5], c0f, s0f);
        PKROT(S.w[2], S.w[6], c0f, s0f);
        PKROT(S.w[3], S.w[7], c0f, s0f);
        // t1: cross-lane (lane ^ 32) on w[0..3] via permlane32_swap
        f2 p[4];
        #pragma unroll
        for (int j = 0; j < 4; ++j) {
            p[j].x = partner32(S.w[j].x, hi);
            p[j].y = partner32(S.w[j].y, hi);
        }
        #pragma unroll
        for (int j = 0; j < 4; ++j)
            S.w[j] = __builtin_elementwise_fma(c1f, S.w[j], b1f * p[j]);
        PKROT(S.w[0], S.w[2], c2f, s2f);
        PKROT(S.w[1], S.w[3], c2f, s2f);
        PKROT(S.w[0], S.w[1], c3xf, s3xf);
        PKROT(S.w[2], S.w[3], c3yf, s3yf);

        // ---- B fragments: (re,im) interleaved K slots, lane-local ----
        H8 b0, b1;
        #pragma unroll
        for (int n = 0; n < 4; ++n) {
            b0.h2[n] = __builtin_amdgcn_cvt_pkrtz(S.w[n].x,     S.w[n].y);
            b1.h2[n] = __builtin_amdgcn_cvt_pkrtz(S.w[4 + n].x, S.w[4 + n].y);
        }

        // ---- U apply: 2 chained MFMAs (K=32), fp32 accumulate ----
        f32x16 acc = __builtin_amdgcn_mfma_f32_32x32x16_f16(A0, b0.h8, kZero, 0, 0, 0);
        acc = __builtin_amdgcn_mfma_f32_32x32x16_f16(A1, b1.h8, acc, 0, 0, 0);
        S.a = acc;
    }

    // ---- probabilities -> clipped output, (b, 16, 64, 64) ----
    float* ob = out + (size_t)b * 65536 + (size_t)row * 64 + xc;
    #pragma unroll
    for (int j = 0; j < 8; ++j) {
        const int amp = (j < 4) ? 4*hi + j : 4*hi + j + 4;
        const float pr = S.w[j].x * S.w[j].x + S.w[j].y * S.w[j].y;
        ob[amp * 4096] = fminf(pr * 8.f, 1.f);
    }
}

extern "C" void kernel_launch(void* const* d_in, const int* in_sizes, int n_in,
                              void* d_out, int out_size, void* d_ws, size_t ws_size,
                              hipStream_t stream) {
    const float* x   = (const float*)d_in[0];
    const float* wts = (const float*)d_in[1];
    float* out = (float*)d_out;
    // 131072 pixels, 2 lanes each: 1024 blocks x 256 threads
    qconv_kernel<<<1024, 256, 0, stream>>>(x, wts, out);
}

// Round 15
// 13.982 us; speedup vs baseline: 1.0907x; 1.0907x over previous
//
#include <hip/hip_runtime.h>

// ---------------------------------------------------------------------------
// Quantum conv2d, MFMA edition v4 (rsq-only Mottonen coefficients).
// == exact R12 winner (14.1 us). R13's bundled v5 tweaks (permlane32_swap,
// padded tile, hoisted zero-acc) regressed to 15.2 and are reverted.
// Row/K convention (validated R8): row 2m = Re(amp), 2m+1 = Im(amp); K slot
// 2n = Re, 2n+1 = Im -> MFMA acc pairs are (Re,Im) of one amp, state = f2[8],
// cascade fully on v_pk_fma_f32, B-pack = cvt_pkrtz(re,im).
// Node coefficients need ZERO v_sqrt: inputs >= 0 so sqrt(q_j) = x_j, and
// interior sqrt(s) = s * rsq(s) with rsq's shared across tree levels.
// 6 rsq/channel total.
// ---------------------------------------------------------------------------

typedef float     f2      __attribute__((ext_vector_type(2)));
typedef __fp16    fp16x2  __attribute__((ext_vector_type(2)));
typedef _Float16  half8_t __attribute__((ext_vector_type(8)));
typedef float     f32x16  __attribute__((ext_vector_type(16)));

union H8   { fp16x2 h2[4]; half8_t h8; };
union AccW { f32x16 a; f2 w[8]; };

// ---------- f2 complex helpers (setup phase: evolve U columns) ----------
__device__ __forceinline__ f2 pkfma(f2 a, f2 b, f2 c) {
    return __builtin_elementwise_fma(a, b, c);
}
__device__ __forceinline__ f2 swap2(f2 v) {
    return __builtin_shufflevector(v, v, 1, 0);
}

struct GateM { f2 m00rr, m00ni, m01rr, m01ni, m10rr, m10ni, m11rr, m11ni; };

__device__ __forceinline__ GateM load_gate(const float* gp) {
    const float4* p = (const float4*)gp;
    const float4 e0 = p[0], e1 = p[1], e2 = p[2], e3 = p[3];
    GateM G;
    G.m00rr = f2{e0.x, e0.y}; G.m00ni = f2{e0.z, e0.w};
    G.m01rr = f2{e1.x, e1.y}; G.m01ni = f2{e1.z, e1.w};
    G.m10rr = f2{e2.x, e2.y}; G.m10ni = f2{e2.z, e2.w};
    G.m11rr = f2{e3.x, e3.y}; G.m11ni = f2{e3.z, e3.w};
    return G;
}

template<int STRIDE>
__device__ __forceinline__ void apply_gate(f2* s, const GateM G) {
    #pragma unroll
    for (int m0 = 0; m0 < 16; ++m0) {
        if (m0 & STRIDE) continue;
        const int m1 = m0 | STRIDE;
        const f2 a = s[m0], b = s[m1];
        const f2 as = swap2(a), bs = swap2(b);
        f2 o0 = G.m00rr * a;
        o0 = pkfma(G.m00ni, as, o0);
        o0 = pkfma(G.m01rr, b,  o0);
        o0 = pkfma(G.m01ni, bs, o0);
        f2 o1 = G.m10rr * a;
        o1 = pkfma(G.m10ni, as, o1);
        o1 = pkfma(G.m11rr, b,  o1);
        o1 = pkfma(G.m11ni, bs, o1);
        s[m0] = o0; s[m1] = o1;
    }
}

template<int BC, int BT>
__device__ __forceinline__ void apply_cnot(f2* s) {
    #pragma unroll
    for (int m = 0; m < 16; ++m) {
        if ((m & BC) && !(m & BT)) {
            const int m2 = m | BT;
            const f2 t = s[m]; s[m] = s[m2]; s[m2] = t;
        }
    }
}

// Packed rotation on (re,im) pairs: a' = c*a - s*b ; b' = s*a + c*b
#define PKROT(a, b, cc, ss) { \
    const f2 _na = __builtin_elementwise_fma(cc, a, -((ss) * (b))); \
    const f2 _nb = __builtin_elementwise_fma(ss, a,  ((cc) * (b))); \
    (a) = _na; (b) = _nb; }

__global__ __launch_bounds__(256, 4) void qconv_kernel(
        const float* __restrict__ x,     // (32, 4, 64, 64)
        const float* __restrict__ wts,   // (4, 2, 4, 3)
        float* __restrict__ out) {       // (32, 16, 64, 64)
    __shared__ float   smat[32 * 16];    // 2 KB packed gate coeffs
    __shared__ float   tile[4 * 4 * 64]; // 4 KB input rows 2ry-1..2ry+2
    __shared__ f2      ucol[4 * 16 * 16];// 8 KB U columns (complex f32)
    __shared__ half8_t ufrag[4 * 2 * 64];// 4 KB A-fragments [ch][mfma][lane]

    const int tid = threadIdx.x;
    const int blk = blockIdx.x;          // 1024 blocks
    const int b  = blk >> 5;             // image
    const int ry = blk & 31;             // rows 2ry, 2ry+1

    // --- stage input tile (coalesced), pad with 0.01 ---
    const float* xb = x + (size_t)b * 16384;
    #pragma unroll
    for (int i = 0; i < 4; ++i) {
        const int e = tid + i * 256;     // [r][ch][col], r=0..3
        const int r = e >> 8, ch = (e >> 6) & 3, col = e & 63;
        const int gy = 2 * ry - 1 + r;
        const int gyc = min(max(gy, 0), 63);
        float val = xb[ch * 4096 + gyc * 64 + col];
        val = ((unsigned)gy < 64u) ? val : 0.01f;
        tile[e] = val;
    }

    // --- build packed Rot matrices (one thread per gate) ---
    if (tid < 32) {
        const float phi   = wts[tid*3 + 0];
        const float theta = wts[tid*3 + 1];
        const float omega = wts[tid*3 + 2];
        float st, ct; __sincosf(0.5f * theta,         &st, &ct);
        float sA, cA; __sincosf(0.5f * (phi + omega), &sA, &cA);
        float sB, cB; __sincosf(0.5f * (phi - omega), &sB, &cB);
        float* g = &smat[tid * 16];
        g[0]  =  cA*ct; g[1]  =  cA*ct; g[2]  =  sA*ct; g[3]  = -sA*ct; // m00
        g[4]  = -cB*st; g[5]  = -cB*st; g[6]  =  sB*st; g[7]  = -sB*st; // m01
        g[8]  =  cB*st; g[9]  =  cB*st; g[10] =  sB*st; g[11] = -sB*st; // m10
        g[12] =  cA*ct; g[13] =  cA*ct; g[14] = -sA*ct; g[15] =  sA*ct; // m11
    }
    __syncthreads();

    // --- evolve U columns: thread t<64 owns (ch = t>>4, col = t&15) ---
    if (tid < 64) {
        const int ch = tid >> 4, col = tid & 15;
        f2 u[16];
        #pragma unroll
        for (int j = 0; j < 16; ++j)
            u[j] = (j == col) ? f2{1.f, 0.f} : f2{0.f, 0.f};
        const float* cb = smat + ch * 128;
        apply_gate<8>(u, load_gate(cb + 0*16));
        apply_gate<4>(u, load_gate(cb + 1*16));
        apply_gate<2>(u, load_gate(cb + 2*16));
        apply_gate<1>(u, load_gate(cb + 3*16));
        apply_cnot<8, 4>(u); apply_cnot<4, 2>(u);
        apply_cnot<2, 1>(u); apply_cnot<1, 8>(u);
        apply_gate<8>(u, load_gate(cb + 4*16));
        apply_gate<4>(u, load_gate(cb + 5*16));
        apply_gate<2>(u, load_gate(cb + 6*16));
        apply_gate<1>(u, load_gate(cb + 7*16));
        apply_cnot<8, 2>(u); apply_cnot<4, 1>(u);
        apply_cnot<2, 8>(u); apply_cnot<1, 4>(u);
        #pragma unroll
        for (int j = 0; j < 16; ++j)
            ucol[(ch * 16 + col) * 16 + j] = u[j];   // ucol[ch][in][out]
    }
    __syncthreads();

    // --- build A-fragments with interleaved (Re,Im) row/K convention ---
    {
        const int ch = tid >> 6, l = tid & 63;
        const int mrow = l & 31, kf = l >> 5;
        const int hr = (mrow >> 2) & 1;
        const int ii = (mrow & 3) | ((mrow >> 3) << 2);
        const int jj = ii >> 1, pr = ii & 1;
        const int amp_out = (jj < 4) ? 4*hr + jj : 4*hr + jj + 4;
        #pragma unroll
        for (int m = 0; m < 2; ++m) {
            half8_t f;
            #pragma unroll
            for (int i = 0; i < 8; ++i) {
                const int n = i >> 1, pk = i & 1;
                const int jin = 4*m + n;
                const int amp_in = (jin < 4) ? 4*kf + jin : 4*kf + jin + 4;
                const f2 e = ucol[(ch * 16 + amp_in) * 16 + amp_out];
                const float val = pr ? (pk ? e.x : e.y) : (pk ? -e.y : e.x);
                f[i] = (_Float16)val;
            }
            ufrag[(ch * 2 + m) * 64 + l] = f;
        }
    }
    __syncthreads();

    // --- main: wave w (0-3) -> row 2ry+(w>>1), cols 32*(w&1)+..; 2 lanes/px ---
    const int wv = tid >> 6, lane = tid & 63;
    const int hi = lane >> 5;                 // amp-half this lane owns
    const int row = 2 * ry + (wv >> 1);
    const int xc = ((wv & 1) << 5) + (lane & 31);
    const int colm = min(max(xc - 1, 0), 63);
    const int colp = min(xc + 1, 63);
    const bool inm = xc > 0, inp = xc < 63;
    const int tr0 = (wv >> 1);                // tile row base for dy=0

    // state: S.w[j] = (Re, Im) of amp alpha(hi, j)
    AccW S;
    #pragma unroll
    for (int j = 0; j < 8; ++j) S.w[j] = f2{0.f, 0.f};
    S.w[0].x = hi ? 0.f : 1.f;                // |0>

    constexpr float EPS = 1e-30f;

    #pragma unroll
    for (int ic = 0; ic < 4; ++ic) {
        // ---- A fragments early: ds_read_b128 latency hides under cascade ----
        const half8_t A0 = ufrag[(ic * 2 + 0) * 64 + lane];
        const half8_t A1 = ufrag[(ic * 2 + 1) * 64 + lane];

        // ---- raw 3x3 patch (values >= 0: sqrt(q_j) == xv[j]) ----
        float xv[9];
        #pragma unroll
        for (int dy = 0; dy < 3; ++dy) {
            const float* rowp = tile + ((tr0 + dy) * 4 + ic) * 64;
            float vm = rowp[colm]; vm = inm ? vm : 0.01f;
            float v0 = rowp[xc];
            float vp = rowp[colp]; vp = inp ? vp : 0.01f;
            xv[dy*3 + 0] = vm;
            xv[dy*3 + 1] = v0;
            xv[dy*3 + 2] = vp;
        }

        // ---- pairwise sums of squares ----
        const float s01 = fmaf(xv[0], xv[0], xv[1]*xv[1]);
        const float s23 = fmaf(xv[2], xv[2], xv[3]*xv[3]);
        const float s45 = fmaf(xv[4], xv[4], xv[5]*xv[5]);
        const float s67 = fmaf(xv[6], xv[6], xv[7]*xv[7]);
        const float s03 = s01 + s23, s47 = s45 + s67, s07 = s03 + s47;
        const float Sf  = fmaf(xv[8], xv[8], s07);

        // ---- per-half raw/sum selection ----
        const float a_  = hi ? xv[4] : xv[0], b_  = hi ? xv[5] : xv[1];
        const float c_  = hi ? xv[6] : xv[2], d_  = hi ? xv[7] : xv[3];
        const float sab = hi ? s45 : s01,     scd = hi ? s67 : s23;

        // ---- 6 rsq, ZERO sqrt ----
        const float rAB = __builtin_amdgcn_rsqf(sab + EPS);
        const float rCD = __builtin_amdgcn_rsqf(scd + EPS);
        const float r03 = __builtin_amdgcn_rsqf(s03 + EPS);
        const float r47 = __builtin_amdgcn_rsqf(s47 + EPS);
        const float r07 = __builtin_amdgcn_rsqf(s07 + EPS);
        const float rS  = __builtin_amdgcn_rsqf(Sf  + EPS);
        const float rS4 = hi ? r47 : r03;

        // ---- node coefficients via telescoped products ----
        const float c0  = s07 * r07 * rS,   s0  = xv[8] * rS;
        const float c1  = s03 * r03 * r07,  s1v = s47 * r47 * r07;
        const float c2e = sab * rAB * rS4,  s2e = scd * rCD * rS4;
        const float c3x = a_ * rAB,         s3x = b_ * rAB;
        const float c3y = c_ * rCD,         s3y = d_ * rCD;
        const float bs1 = hi ? s1v : -s1v;

        // broadcast to packed coeffs
        const f2 c0f = f2{c0, c0},   s0f = f2{s0, s0};
        const f2 c1f = f2{c1, c1},   b1f = f2{bs1, bs1};
        const f2 c2f = f2{c2e, c2e}, s2f = f2{s2e, s2e};
        const f2 c3xf = f2{c3x, c3x}, s3xf = f2{s3x, s3x};
        const f2 c3yf = f2{c3y, c3y}, s3yf = f2{s3y, s3y};

        // ---- cascade, fully packed ----
        PKROT(S.w[0], S.w[4], c0f, s0f);
        PKROT(S.w[1], S.w[5], c0f, s0f);
        PKROT(S.w[2], S.w[6], c0f, s0f);
        PKROT(S.w[3], S.w[7], c0f, s0f);
        // t1: cross-lane (xor32) on w[0..3]; b=1 block identity
        f2 p[4];
        #pragma unroll
        for (int j = 0; j < 4; ++j) {
            p[j].x = __shfl_xor(S.w[j].x, 32);
            p[j].y = __shfl_xor(S.w[j].y, 32);
        }
        #pragma unroll
        for (int j = 0; j < 4; ++j)
            S.w[j] = __builtin_elementwise_fma(c1f, S.w[j], b1f * p[j]);
        PKROT(S.w[0], S.w[2], c2f, s2f);
        PKROT(S.w[1], S.w[3], c2f, s2f);
        PKROT(S.w[0], S.w[1], c3xf, s3xf);
        PKROT(S.w[2], S.w[3], c3yf, s3yf);

        // ---- B fragments: (re,im) interleaved K slots, lane-local ----
        H8 b0, b1;
        #pragma unroll
        for (int n = 0; n < 4; ++n) {
            b0.h2[n] = __builtin_amdgcn_cvt_pkrtz(S.w[n].x,     S.w[n].y);
            b1.h2[n] = __builtin_amdgcn_cvt_pkrtz(S.w[4 + n].x, S.w[4 + n].y);
        }

        // ---- U apply: 2 chained MFMAs (K=32), fp32 accumulate ----
        f32x16 acc;
        #pragma unroll
        for (int i = 0; i < 16; ++i) acc[i] = 0.f;
        acc = __builtin_amdgcn_mfma_f32_32x32x16_f16(A0, b0.h8, acc, 0, 0, 0);
        acc = __builtin_amdgcn_mfma_f32_32x32x16_f16(A1, b1.h8, acc, 0, 0, 0);
        S.a = acc;
    }

    // ---- probabilities -> clipped output, (b, 16, 64, 64) ----
    float* ob = out + (size_t)b * 65536 + (size_t)row * 64 + xc;
    #pragma unroll
    for (int j = 0; j < 8; ++j) {
        const int amp = (j < 4) ? 4*hi + j : 4*hi + j + 4;
        const float pr = S.w[j].x * S.w[j].x + S.w[j].y * S.w[j].y;
        ob[amp * 4096] = fminf(pr * 8.f, 1.f);
    }
}

extern "C" void kernel_launch(void* const* d_in, const int* in_sizes, int n_in,
                              void* d_out, int out_size, void* d_ws, size_t ws_size,
                              hipStream_t stream) {
    const float* x   = (const float*)d_in[0];
    const float* wts = (const float*)d_in[1];
    float* out = (float*)d_out;
    // 131072 pixels, 2 lanes each: 1024 blocks x 256 threads
    qconv_kernel<<<1024, 256, 0, stream>>>(x, wts, out);
}